// Round 1
// baseline (29259.705 us; speedup 1.0000x reference)
//
#include <hip/hip_runtime.h>

#define RD     128     // residual / skip channels
#define TT     128     // time tile per block
#define TLEN   16384   // T
#define NB     8       // batch
#define NLAYER 63
#define N0SKIP 27
#define QD     256     // final output channels

// ---------------------------------------------------------------------------
// Register-tiled 128x128x128 GEMM partial: acc[c][t] += sum_i W[i][c]*A[i][t]
// 256 threads = 16x16 thread grid, each thread owns an 8x8 output tile.
// ---------------------------------------------------------------------------
__device__ __forceinline__ void gemm_tile(const float (*__restrict__ A)[TT],
                                          const float (*__restrict__ W)[RD],
                                          int tc, int tt, float acc[8][8]) {
#pragma unroll 4
  for (int i = 0; i < RD; ++i) {
    const float4 w0 = *(const float4*)&W[i][tc * 8];
    const float4 w1 = *(const float4*)&W[i][tc * 8 + 4];
    const float4 x0 = *(const float4*)&A[i][tt * 8];
    const float4 x1 = *(const float4*)&A[i][tt * 8 + 4];
    const float wv[8] = {w0.x, w0.y, w0.z, w0.w, w1.x, w1.y, w1.z, w1.w};
    const float xv[8] = {x0.x, x0.y, x0.z, x0.w, x1.x, x1.y, x1.z, x1.w};
#pragma unroll
    for (int a = 0; a < 8; ++a)
#pragma unroll
      for (int b = 0; b < 8; ++b)
        acc[a][b] = fmaf(wv[a], xv[b], acc[a][b]);
  }
}

// ---------------------------------------------------------------------------
// Causal conv: x [B,1,T] -> y [B,RD,T], kernel 25, pad 12.
// ---------------------------------------------------------------------------
__global__ __launch_bounds__(256) void causal_kernel(const float* __restrict__ x,
                                                     const float* __restrict__ w,
                                                     const float* __restrict__ bias,
                                                     float* __restrict__ y) {
  __shared__ float ws_[RD * 25];
  __shared__ float bs[RD];
  const int tid = threadIdx.x;
  for (int idx = tid; idx < RD * 25; idx += 256) ws_[idx] = w[idx];
  if (tid < RD) bs[tid] = bias[tid];
  __syncthreads();

  const int b = blockIdx.x >> 6;              // T/256 = 64 blocks per batch
  const int t = ((blockIdx.x & 63) << 8) + tid;
  const float* xb = x + (size_t)b * TLEN;

  float xw[25];
#pragma unroll
  for (int k = 0; k < 25; ++k) {
    const int tg = t + k - 12;
    xw[k] = ((unsigned)tg < (unsigned)TLEN) ? xb[tg] : 0.f;
  }
  float* yb = y + (size_t)b * RD * TLEN + t;
  for (int c = 0; c < RD; ++c) {
    float s = bs[c];
#pragma unroll
    for (int k = 0; k < 25; ++k) s = fmaf(ws_[c * 25 + k], xw[k], s);
    yb[(size_t)c * TLEN] = s;
  }
}

// ---------------------------------------------------------------------------
// One WaveNet layer, fully fused:
//   h = relu(dconv(relu(x)))                (3 shifted matmuls)
//   x_out = dense(h) + dense_b + x_in       (residual)
//   skip += skip_mm(h) + skip_b             (if do_skip)
// ---------------------------------------------------------------------------
__global__ __launch_bounds__(256, 1) void layer_kernel(
    const float* __restrict__ x_in, float* __restrict__ x_out,
    float* __restrict__ skip,
    const float* __restrict__ wconvT,   // [3][i][c]
    const float* __restrict__ bconv,
    const float* __restrict__ wdenseT,  // [i][o]
    const float* __restrict__ bdense,
    const float* __restrict__ wskipT,   // [i][o]
    const float* __restrict__ bskip,
    int dil, int do_skip) {
  __shared__ float A[RD][TT];   // 64 KB: shifted relu(x), then h
  __shared__ float W[RD][RD];   // 64 KB: current weight slice (transposed)

  const int tid = threadIdx.x;
  const int b   = blockIdx.x >> 7;           // T/TT = 128 tiles per batch
  const int t0  = (blockIdx.x & 127) * TT;
  const int tc  = tid >> 4, tt = tid & 15;
  const float* xb = x_in + (size_t)b * RD * TLEN;

  float acc[8][8];
#pragma unroll
  for (int a = 0; a < 8; ++a)
#pragma unroll
    for (int c = 0; c < 8; ++c) acc[a][c] = 0.f;

  // ---- dilated conv as 3 shifted matmuls ----
  for (int k = 0; k < 3; ++k) {
    __syncthreads();
    const int shift = (k - 1) * dil;
    for (int idx = tid; idx < RD * TT; idx += 256) {
      const int i = idx >> 7, t = idx & (TT - 1);
      const int tg = t0 + t + shift;
      float v = 0.f;
      if ((unsigned)tg < (unsigned)TLEN) v = xb[(size_t)i * TLEN + tg];
      A[i][t] = v > 0.f ? v : 0.f;
    }
    const float* wk = wconvT + (size_t)k * RD * RD;
    for (int idx = tid; idx < RD * RD; idx += 256) (&W[0][0])[idx] = wk[idx];
    __syncthreads();
    gemm_tile(A, W, tc, tt, acc);
  }

  // ---- h = relu(acc + bconv) -> LDS; stage dense weights ----
  __syncthreads();
#pragma unroll
  for (int a = 0; a < 8; ++a) {
    const float bb = bconv[tc * 8 + a];
#pragma unroll
    for (int c = 0; c < 8; ++c) {
      const float v = acc[a][c] + bb;
      A[tc * 8 + a][tt * 8 + c] = v > 0.f ? v : 0.f;
    }
  }
  for (int idx = tid; idx < RD * RD; idx += 256) (&W[0][0])[idx] = wdenseT[idx];
  __syncthreads();

  // ---- dense matmul + residual ----
#pragma unroll
  for (int a = 0; a < 8; ++a)
#pragma unroll
    for (int c = 0; c < 8; ++c) acc[a][c] = 0.f;
  gemm_tile(A, W, tc, tt, acc);

  {
    float* yo = x_out + (size_t)b * RD * TLEN + t0 + tt * 8;
    const float* xi = x_in + (size_t)b * RD * TLEN + t0 + tt * 8;
#pragma unroll
    for (int a = 0; a < 8; ++a) {
      const int o = tc * 8 + a;
      const float bb = bdense[o];
      float4 v0 = *(const float4*)&xi[(size_t)o * TLEN];
      float4 v1 = *(const float4*)&xi[(size_t)o * TLEN + 4];
      v0.x += acc[a][0] + bb; v0.y += acc[a][1] + bb;
      v0.z += acc[a][2] + bb; v0.w += acc[a][3] + bb;
      v1.x += acc[a][4] + bb; v1.y += acc[a][5] + bb;
      v1.z += acc[a][6] + bb; v1.w += acc[a][7] + bb;
      *(float4*)&yo[(size_t)o * TLEN]     = v0;
      *(float4*)&yo[(size_t)o * TLEN + 4] = v1;
    }
  }

  // ---- skip matmul + global accumulate ----
  if (do_skip) {
    __syncthreads();
    for (int idx = tid; idx < RD * RD; idx += 256) (&W[0][0])[idx] = wskipT[idx];
    __syncthreads();
#pragma unroll
    for (int a = 0; a < 8; ++a)
#pragma unroll
      for (int c = 0; c < 8; ++c) acc[a][c] = 0.f;
    gemm_tile(A, W, tc, tt, acc);

    float* sp = skip + (size_t)b * RD * TLEN + t0 + tt * 8;
#pragma unroll
    for (int a = 0; a < 8; ++a) {
      const int o = tc * 8 + a;
      const float bb = bskip[o];
      float4 v0 = *(const float4*)&sp[(size_t)o * TLEN];
      float4 v1 = *(const float4*)&sp[(size_t)o * TLEN + 4];
      v0.x += acc[a][0] + bb; v0.y += acc[a][1] + bb;
      v0.z += acc[a][2] + bb; v0.w += acc[a][3] + bb;
      v1.x += acc[a][4] + bb; v1.y += acc[a][5] + bb;
      v1.z += acc[a][6] + bb; v1.w += acc[a][7] + bb;
      *(float4*)&sp[(size_t)o * TLEN]     = v0;
      *(float4*)&sp[(size_t)o * TLEN + 4] = v1;
    }
  }
}

// ---------------------------------------------------------------------------
// Post: out = post2( relu(post1(relu(skip))) ), out [B,QD,T]
// ---------------------------------------------------------------------------
__global__ __launch_bounds__(256, 1) void post_kernel(
    const float* __restrict__ skip,
    const float* __restrict__ p1T, const float* __restrict__ p1b,
    const float* __restrict__ p2T, const float* __restrict__ p2b,
    float* __restrict__ out) {
  __shared__ float A[RD][TT];
  __shared__ float W[RD][RD];
  const int tid = threadIdx.x;
  const int b   = blockIdx.x >> 7;
  const int t0  = (blockIdx.x & 127) * TT;
  const int tc  = tid >> 4, tt = tid & 15;

  for (int idx = tid; idx < RD * TT; idx += 256) {
    const int i = idx >> 7, t = idx & (TT - 1);
    const float v = skip[((size_t)b * RD + i) * TLEN + t0 + t];
    A[i][t] = v > 0.f ? v : 0.f;
  }
  for (int idx = tid; idx < RD * RD; idx += 256) (&W[0][0])[idx] = p1T[idx];
  __syncthreads();

  float acc[8][8];
#pragma unroll
  for (int a = 0; a < 8; ++a)
#pragma unroll
    for (int c = 0; c < 8; ++c) acc[a][c] = 0.f;
  gemm_tile(A, W, tc, tt, acc);
  __syncthreads();

#pragma unroll
  for (int a = 0; a < 8; ++a) {
    const float bb = p1b[tc * 8 + a];
#pragma unroll
    for (int c = 0; c < 8; ++c) {
      const float v = acc[a][c] + bb;
      A[tc * 8 + a][tt * 8 + c] = v > 0.f ? v : 0.f;
    }
  }

  for (int half = 0; half < 2; ++half) {
    for (int idx = tid; idx < RD * RD; idx += 256) {
      const int i = idx >> 7, o = idx & (RD - 1);
      W[i][o] = p2T[(size_t)i * QD + half * RD + o];
    }
    __syncthreads();
#pragma unroll
    for (int a = 0; a < 8; ++a)
#pragma unroll
      for (int c = 0; c < 8; ++c) acc[a][c] = 0.f;
    gemm_tile(A, W, tc, tt, acc);

    float* yo = out + ((size_t)b * QD + half * RD) * TLEN + t0 + tt * 8;
#pragma unroll
    for (int a = 0; a < 8; ++a) {
      const int o = tc * 8 + a;
      const float bb = p2b[half * RD + o];
      float4 v0, v1;
      v0.x = acc[a][0] + bb; v0.y = acc[a][1] + bb;
      v0.z = acc[a][2] + bb; v0.w = acc[a][3] + bb;
      v1.x = acc[a][4] + bb; v1.y = acc[a][5] + bb;
      v1.z = acc[a][6] + bb; v1.w = acc[a][7] + bb;
      *(float4*)&yo[(size_t)o * TLEN]     = v0;
      *(float4*)&yo[(size_t)o * TLEN + 4] = v1;
    }
    __syncthreads();
  }
}

// ---------------------------------------------------------------------------
// Weight transposes (run once per call; ~5M elements, negligible)
// dcnn: [L][c][i][3] -> [L][3][i][c]
// ---------------------------------------------------------------------------
__global__ __launch_bounds__(256) void tr_conv_kernel(const float* __restrict__ in,
                                                      float* __restrict__ out, int total) {
  const int idx = blockIdx.x * 256 + threadIdx.x;
  if (idx >= total) return;
  const int c = idx & 127;
  const int i = (idx >> 7) & 127;
  const int r = idx >> 14;
  const int k = r % 3, l = r / 3;
  out[idx] = in[(((size_t)l * RD + c) * RD + i) * 3 + k];
}

// batched [N][O][I] -> [N][I][O]
__global__ __launch_bounds__(256) void tr2d_kernel(const float* __restrict__ in,
                                                   float* __restrict__ out,
                                                   int O, int I, int total) {
  const int idx = blockIdx.x * 256 + threadIdx.x;
  if (idx >= total) return;
  const int o = idx % O;
  const int rest = idx / O;
  const int i = rest % I;
  const int n = rest / I;
  out[idx] = in[((size_t)n * O + o) * I + i];
}

// ---------------------------------------------------------------------------
extern "C" void kernel_launch(void* const* d_in, const int* in_sizes, int n_in,
                              void* d_out, int out_size, void* d_ws, size_t ws_size,
                              hipStream_t stream) {
  const float* x        = (const float*)d_in[0];
  const float* causal_w = (const float*)d_in[1];
  const float* causal_b = (const float*)d_in[2];
  const float* dcnn_w   = (const float*)d_in[3];
  const float* dcnn_b   = (const float*)d_in[4];
  const float* dense_w  = (const float*)d_in[5];
  const float* dense_b  = (const float*)d_in[6];
  const float* skip_w   = (const float*)d_in[7];
  const float* skip_b   = (const float*)d_in[8];
  const float* post1_w  = (const float*)d_in[9];
  const float* post1_b  = (const float*)d_in[10];
  const float* post2_w  = (const float*)d_in[11];
  const float* post2_b  = (const float*)d_in[12];
  float* out = (float*)d_out;

  const size_t XN = (size_t)NB * RD * TLEN;        // 16.78M floats
  float* ws   = (float*)d_ws;
  float* xA   = ws;
  float* xB   = xA + XN;
  float* skp  = xB + XN;
  float* wcT  = skp + XN;                          // 63*3*128*128
  float* wdT  = wcT + (size_t)NLAYER * 3 * RD * RD;
  float* wsT  = wdT + (size_t)NLAYER * RD * RD;
  float* p1T  = wsT + (size_t)NLAYER * RD * RD;
  float* p2T  = p1T + RD * RD;                     // [128][256]

  // weight transposes
  {
    const int tconv = NLAYER * 3 * RD * RD;
    tr_conv_kernel<<<(tconv + 255) / 256, 256, 0, stream>>>(dcnn_w, wcT, tconv);
    const int t2 = NLAYER * RD * RD;
    tr2d_kernel<<<(t2 + 255) / 256, 256, 0, stream>>>(dense_w, wdT, RD, RD, t2);
    tr2d_kernel<<<(t2 + 255) / 256, 256, 0, stream>>>(skip_w, wsT, RD, RD, t2);
    tr2d_kernel<<<(RD * RD + 255) / 256, 256, 0, stream>>>(post1_w, p1T, RD, RD, RD * RD);
    tr2d_kernel<<<(QD * RD + 255) / 256, 256, 0, stream>>>(post2_w, p2T, QD, RD, QD * RD);
  }

  // causal conv + zero the skip accumulator
  causal_kernel<<<NB * (TLEN / 256), 256, 0, stream>>>(x, causal_w, causal_b, xA);
  hipMemsetAsync(skp, 0, XN * sizeof(float), stream);

  // 63 fused layers, ping-pong x buffers
  const float* src = xA;
  float* dst = xB;
  for (int l = 0; l < NLAYER; ++l) {
    const int dil = 1 << (l % 9);
    layer_kernel<<<NB * (TLEN / TT), 256, 0, stream>>>(
        src, dst, skp,
        wcT + (size_t)l * 3 * RD * RD, dcnn_b + (size_t)l * RD,
        wdT + (size_t)l * RD * RD,     dense_b + (size_t)l * RD,
        wsT + (size_t)l * RD * RD,     skip_b + (size_t)l * RD,
        dil, (l >= N0SKIP) ? 1 : 0);
    const float* tmp = src; src = dst; dst = (float*)tmp;
  }

  // post network
  post_kernel<<<NB * (TLEN / TT), 256, 0, stream>>>(skp, p1T, post1_b, p2T, post2_b, out);
}

// Round 2
// 5231.223 us; speedup vs baseline: 5.5933x; 5.5933x over previous
//
#include <hip/hip_runtime.h>

#define RD     128
#define TT     128
#define TLEN   16384
#define NB     8
#define NLAYER 63
#define N0SKIP 27
#define QD     256
#define PADR   136   // padded LDS row (bf16 elems): +16B kills bank conflicts

typedef short bf16x8 __attribute__((ext_vector_type(8)));
typedef float f32x4  __attribute__((ext_vector_type(4)));

__device__ __forceinline__ unsigned short f2bf(float f) {
  unsigned u = __float_as_uint(f);
  u += 0x7fffu + ((u >> 16) & 1u);           // round-to-nearest-even
  return (unsigned short)(u >> 16);
}
__device__ __forceinline__ short f2bf_relu(float f) {
  f = f > 0.f ? f : 0.f;
  unsigned u = __float_as_uint(f);
  u += 0x7fffu + ((u >> 16) & 1u);
  return (short)(u >> 16);
}

// ---------------------------------------------------------------------------
// 128x(64c x 64t) MFMA GEMM: acc[ct][tt] += W[c][i] * H[i][t]
// W: bf16 global [128 c][128 i] row-major (A-frag = 16B contiguous load)
// H: LDS [t][i] bf16, rows padded to PADR
// ---------------------------------------------------------------------------
__device__ __forceinline__ void mfma_gemm(const unsigned short* __restrict__ aw,
                                          const short* sx, int rowbase,
                                          int c0w, int t0w, int n, int q,
                                          f32x4 (&acc)[4][4]) {
#pragma unroll
  for (int ks = 0; ks < 4; ++ks) {
    const int i0 = ks * 32 + q * 8;
    bf16x8 a[4], bb[4];
#pragma unroll
    for (int ct = 0; ct < 4; ++ct)
      a[ct] = *(const bf16x8*)&aw[(size_t)(c0w + ct * 16 + n) * RD + i0];
#pragma unroll
    for (int tt = 0; tt < 4; ++tt)
      bb[tt] = *(const bf16x8*)&sx[(rowbase + t0w + tt * 16 + n) * PADR + i0];
#pragma unroll
    for (int ct = 0; ct < 4; ++ct)
#pragma unroll
      for (int tt = 0; tt < 4; ++tt)
        acc[ct][tt] = __builtin_amdgcn_mfma_f32_16x16x32_bf16(a[ct], bb[tt],
                                                              acc[ct][tt], 0, 0, 0);
  }
}

__device__ __forceinline__ void zero_acc(f32x4 (&acc)[4][4]) {
#pragma unroll
  for (int i = 0; i < 4; ++i)
#pragma unroll
    for (int j = 0; j < 4; ++j) acc[i][j] = (f32x4){0.f, 0.f, 0.f, 0.f};
}

// stage nrows of relu(x) (fp32 global [t][c]) into LDS bf16 [row][i]
__device__ __forceinline__ void stage_rows(short* sx, int rowbase,
                                           const float* __restrict__ xb,
                                           int tstart, int nrows, int tid) {
  for (int idx = tid; idx < nrows * 32; idx += 256) {
    const int r = idx >> 5, c4 = (idx & 31) << 2;
    const int tg = tstart + r;
    float4 v = make_float4(0.f, 0.f, 0.f, 0.f);
    if ((unsigned)tg < (unsigned)TLEN)
      v = *(const float4*)&xb[(size_t)tg * RD + c4];
    short4 o;
    o.x = f2bf_relu(v.x); o.y = f2bf_relu(v.y);
    o.z = f2bf_relu(v.z); o.w = f2bf_relu(v.w);
    *(short4*)&sx[(rowbase + r) * PADR + c4] = o;
  }
}

// relu(acc + bias) -> LDS bf16 [t][c] (D layout: c = q*4+reg, t = n)
__device__ __forceinline__ void store_act_bf16(short* dst, const f32x4 (&acc)[4][4],
                                               const float* __restrict__ bias,
                                               int c0w, int t0w, int n, int q) {
#pragma unroll
  for (int ct = 0; ct < 4; ++ct) {
    const int c = c0w + ct * 16 + q * 4;
    const float4 bb = *(const float4*)&bias[c];
#pragma unroll
    for (int tt = 0; tt < 4; ++tt) {
      const int t = t0w + tt * 16 + n;
      const f32x4 A = acc[ct][tt];
      short4 o;
      o.x = f2bf_relu(A[0] + bb.x);
      o.y = f2bf_relu(A[1] + bb.y);
      o.z = f2bf_relu(A[2] + bb.z);
      o.w = f2bf_relu(A[3] + bb.w);
      *(short4*)&dst[t * PADR + c] = o;
    }
  }
}

// dst[t][c] = src[t][c] + acc + bias   (fp32 global tiles, [T][C] layout)
__device__ __forceinline__ void epi_accum(float* __restrict__ dst,
                                          const float* __restrict__ src,
                                          const float* __restrict__ bias,
                                          const f32x4 (&acc)[4][4],
                                          int c0w, int t0w, int n, int q) {
#pragma unroll
  for (int ct = 0; ct < 4; ++ct) {
    const int c = c0w + ct * 16 + q * 4;
    const float4 bb = *(const float4*)&bias[c];
#pragma unroll
    for (int tt = 0; tt < 4; ++tt) {
      const int t = t0w + tt * 16 + n;
      float4 r = *(const float4*)&src[(size_t)t * RD + c];
      const f32x4 A = acc[ct][tt];
      r.x += A[0] + bb.x; r.y += A[1] + bb.y;
      r.z += A[2] + bb.z; r.w += A[3] + bb.w;
      *(float4*)&dst[(size_t)t * RD + c] = r;
    }
  }
}

// ---------------------------------------------------------------------------
// Fused WaveNet layer (bf16 MFMA). x/skip fp32 [B][T][C].
// ---------------------------------------------------------------------------
__global__ __launch_bounds__(256, 2) void layer_kernel(
    const float* __restrict__ x_in, float* __restrict__ x_out,
    float* __restrict__ skip,
    const unsigned short* __restrict__ wconv,   // [3][128][128] bf16
    const float* __restrict__ bconv,
    const unsigned short* __restrict__ wdense, const float* __restrict__ bdense,
    const unsigned short* __restrict__ wskip,  const float* __restrict__ bskip,
    int dil, int do_skip) {
  __shared__ short sx[256 * PADR];             // 69.6 KB -> 2 blocks/CU

  const int tid = threadIdx.x;
  const int b   = blockIdx.x >> 7;
  const int t0  = (blockIdx.x & 127) << 7;
  const int lane = tid & 63;
  const int n = lane & 15, q = lane >> 4;
  const int w = tid >> 6;
  const int c0w = (w & 1) * 64, t0w = (w >> 1) * 64;
  const float* xb = x_in + (size_t)b * TLEN * RD;

  f32x4 acc[4][4];
  zero_acc(acc);

  if (dil <= 64) {
    // haloed tile: rows [t0-d, t0+128+d), tap k reads row t + k*d
    stage_rows(sx, 0, xb, t0 - dil, 128 + 2 * dil, tid);
    __syncthreads();
    for (int k = 0; k < 3; ++k)
      mfma_gemm(wconv + (size_t)k * RD * RD, sx, k * dil, c0w, t0w, n, q, acc);
  } else {
    // d in {128, 256}: per-tap staging, double-buffered
    stage_rows(sx, 0, xb, t0 - dil, 128, tid);
    __syncthreads();
    stage_rows(sx, 128, xb, t0, 128, tid);
    mfma_gemm(wconv, sx, 0, c0w, t0w, n, q, acc);
    __syncthreads();
    stage_rows(sx, 0, xb, t0 + dil, 128, tid);
    mfma_gemm(wconv + (size_t)RD * RD, sx, 128, c0w, t0w, n, q, acc);
    __syncthreads();
    mfma_gemm(wconv + (size_t)2 * RD * RD, sx, 0, c0w, t0w, n, q, acc);
  }
  __syncthreads();

  // h = relu(conv + bconv) -> LDS [t][c]
  store_act_bf16(sx, acc, bconv, c0w, t0w, n, q);
  __syncthreads();

  // dense + residual
  zero_acc(acc);
  mfma_gemm(wdense, sx, 0, c0w, t0w, n, q, acc);
  {
    float* xo = x_out + ((size_t)b * TLEN + t0) * RD;
    const float* xi = x_in + ((size_t)b * TLEN + t0) * RD;
    epi_accum(xo, xi, bdense, acc, c0w, t0w, n, q);
  }

  // skip accumulate
  if (do_skip) {
    zero_acc(acc);
    mfma_gemm(wskip, sx, 0, c0w, t0w, n, q, acc);
    float* sp = skip + ((size_t)b * TLEN + t0) * RD;
    epi_accum(sp, sp, bskip, acc, c0w, t0w, n, q);
  }
}

// ---------------------------------------------------------------------------
// Causal conv: x [B,1,T] -> y fp32 [B][T][C], kernel 25 pad 12
// ---------------------------------------------------------------------------
__global__ __launch_bounds__(256) void causal_kernel(const float* __restrict__ x,
                                                     const float* __restrict__ w,
                                                     const float* __restrict__ bias,
                                                     float* __restrict__ y) {
  __shared__ float xw[152];
  __shared__ float wl[RD * 25];
  __shared__ float bl[RD];
  const int tid = threadIdx.x;
  const int b   = blockIdx.x >> 7;
  const int t0  = (blockIdx.x & 127) << 7;
  for (int i = tid; i < RD * 25; i += 256) wl[i] = w[i];
  if (tid < RD) bl[tid] = bias[tid];
  for (int i = tid; i < 152; i += 256) {
    const int tg = t0 - 12 + i;
    xw[i] = ((unsigned)tg < (unsigned)TLEN) ? x[(size_t)b * TLEN + tg] : 0.f;
  }
  __syncthreads();
  const int c = tid & 127, tp = tid >> 7;
  float* yb = y + ((size_t)b * TLEN + t0) * RD + c;
  const float bc = bl[c];
  for (int i = 0; i < 64; ++i) {
    const int tl = i * 2 + tp;
    float s = bc;
#pragma unroll
    for (int k = 0; k < 25; ++k) s = fmaf(wl[c * 25 + k], xw[tl + k], s);
    yb[(size_t)tl * RD] = s;
  }
}

// ---------------------------------------------------------------------------
// Post: out[B][QD][T] = post2(relu(post1(relu(skip))))
// ---------------------------------------------------------------------------
__global__ __launch_bounds__(256, 1) void post_kernel(
    const float* __restrict__ skip,
    const unsigned short* __restrict__ p1, const float* __restrict__ p1b,
    const unsigned short* __restrict__ p2, const float* __restrict__ p2b,
    float* __restrict__ out) {
  __shared__ short sb[128 * PADR];
  __shared__ short h1[128 * PADR];
  __shared__ float ost[128 * 132];

  const int tid = threadIdx.x;
  const int b   = blockIdx.x >> 7;
  const int t0  = (blockIdx.x & 127) << 7;
  const int lane = tid & 63;
  const int n = lane & 15, q = lane >> 4;
  const int w = tid >> 6;
  const int c0w = (w & 1) * 64, t0w = (w >> 1) * 64;
  const float* skb = skip + ((size_t)b * TLEN + t0) * RD;

  for (int idx = tid; idx < 128 * 32; idx += 256) {
    const int r = idx >> 5, c4 = (idx & 31) << 2;
    float4 v = *(const float4*)&skb[(size_t)r * RD + c4];
    short4 o;
    o.x = f2bf_relu(v.x); o.y = f2bf_relu(v.y);
    o.z = f2bf_relu(v.z); o.w = f2bf_relu(v.w);
    *(short4*)&sb[r * PADR + c4] = o;
  }
  __syncthreads();

  f32x4 acc[4][4];
  zero_acc(acc);
  mfma_gemm(p1, sb, 0, c0w, t0w, n, q, acc);
  store_act_bf16(h1, acc, p1b, c0w, t0w, n, q);
  __syncthreads();

  for (int half = 0; half < 2; ++half) {
    zero_acc(acc);
    mfma_gemm(p2 + (size_t)half * RD * RD, h1, 0, c0w, t0w, n, q, acc);
#pragma unroll
    for (int ct = 0; ct < 4; ++ct) {
      const int c = c0w + ct * 16 + q * 4;
      const float4 bb = *(const float4*)&p2b[half * RD + c];
#pragma unroll
      for (int tt = 0; tt < 4; ++tt) {
        const int t = t0w + tt * 16 + n;
        const f32x4 A = acc[ct][tt];
        ost[(c + 0) * 132 + t] = A[0] + bb.x;
        ost[(c + 1) * 132 + t] = A[1] + bb.y;
        ost[(c + 2) * 132 + t] = A[2] + bb.z;
        ost[(c + 3) * 132 + t] = A[3] + bb.w;
      }
    }
    __syncthreads();
    float* ob = out + ((size_t)b * QD + half * RD) * TLEN + t0;
    for (int idx = tid; idx < 128 * 32; idx += 256) {
      const int r = idx >> 5, t4 = (idx & 31) << 2;
      const float4 v = *(const float4*)&ost[r * 132 + t4];
      *(float4*)&ob[(size_t)r * TLEN + t4] = v;
    }
    __syncthreads();
  }
}

// ---------------------------------------------------------------------------
// Weight prep: fp32 -> bf16 (+ conv relayout [L][co][ci][3] -> [L][3][co][ci])
// ---------------------------------------------------------------------------
__global__ __launch_bounds__(256) void cvt_kernel(const float* __restrict__ in,
                                                  unsigned short* __restrict__ out,
                                                  int total) {
  const int i = blockIdx.x * 256 + threadIdx.x;
  if (i < total) out[i] = f2bf(in[i]);
}
__global__ __launch_bounds__(256) void cvt_conv_kernel(const float* __restrict__ in,
                                                       unsigned short* __restrict__ out,
                                                       int total) {
  const int idx = blockIdx.x * 256 + threadIdx.x;
  if (idx >= total) return;
  const int ci = idx & 127, co = (idx >> 7) & 127, lk = idx >> 14;
  const int k = lk % 3, l = lk / 3;
  out[idx] = f2bf(in[(((size_t)l * RD + co) * RD + ci) * 3 + k]);
}

// ---------------------------------------------------------------------------
extern "C" void kernel_launch(void* const* d_in, const int* in_sizes, int n_in,
                              void* d_out, int out_size, void* d_ws, size_t ws_size,
                              hipStream_t stream) {
  const float* x        = (const float*)d_in[0];
  const float* causal_w = (const float*)d_in[1];
  const float* causal_b = (const float*)d_in[2];
  const float* dcnn_w   = (const float*)d_in[3];
  const float* dcnn_b   = (const float*)d_in[4];
  const float* dense_w  = (const float*)d_in[5];
  const float* dense_b  = (const float*)d_in[6];
  const float* skip_w   = (const float*)d_in[7];
  const float* skip_b   = (const float*)d_in[8];
  const float* post1_w  = (const float*)d_in[9];
  const float* post1_b  = (const float*)d_in[10];
  const float* post2_w  = (const float*)d_in[11];
  const float* post2_b  = (const float*)d_in[12];
  float* out = (float*)d_out;

  const size_t XN = (size_t)NB * TLEN * RD;   // 16.78M
  float* ws  = (float*)d_ws;
  float* xA  = ws;
  float* xB  = xA + XN;
  float* skp = xB + XN;
  unsigned short* wc  = (unsigned short*)(skp + XN);
  unsigned short* wd  = wc  + (size_t)NLAYER * 3 * RD * RD;
  unsigned short* wsk = wd  + (size_t)NLAYER * RD * RD;
  unsigned short* p1  = wsk + (size_t)NLAYER * RD * RD;
  unsigned short* p2  = p1  + RD * RD;

  const int tconv = NLAYER * 3 * RD * RD;
  const int t2    = NLAYER * RD * RD;
  cvt_conv_kernel<<<(tconv + 255) / 256, 256, 0, stream>>>(dcnn_w, wc, tconv);
  cvt_kernel<<<(t2 + 255) / 256, 256, 0, stream>>>(dense_w, wd, t2);
  cvt_kernel<<<(t2 + 255) / 256, 256, 0, stream>>>(skip_w, wsk, t2);
  cvt_kernel<<<(RD * RD + 255) / 256, 256, 0, stream>>>(post1_w, p1, RD * RD);
  cvt_kernel<<<(QD * RD + 255) / 256, 256, 0, stream>>>(post2_w, p2, QD * RD);

  causal_kernel<<<NB * (TLEN / TT), 256, 0, stream>>>(x, causal_w, causal_b, xA);
  hipMemsetAsync(skp, 0, XN * sizeof(float), stream);

  const float* src = xA;
  float* dst = xB;
  for (int l = 0; l < NLAYER; ++l) {
    const int dil = 1 << (l % 9);
    layer_kernel<<<NB * (TLEN / TT), 256, 0, stream>>>(
        src, dst, skp,
        wc  + (size_t)l * 3 * RD * RD, dcnn_b  + (size_t)l * RD,
        wd  + (size_t)l * RD * RD,     dense_b + (size_t)l * RD,
        wsk + (size_t)l * RD * RD,     skip_b  + (size_t)l * RD,
        dil, (l >= N0SKIP) ? 1 : 0);
    const float* tmp = src; src = dst; dst = (float*)tmp;
  }

  post_kernel<<<NB * (TLEN / TT), 256, 0, stream>>>(skp, p1, post1_b, p2, post2_b, out);
}